// Round 6
// baseline (1656.638 us; speedup 1.0000x reference)
//
#include <hip/hip_runtime.h>

// LGA3: 3 chained local-guided-aggregation passes, rolling-accumulator stencil.
// Cost planes staged to LDS (double-buffered global_load_lds, as R4); weights
// software-pipelined through a 2x15-register parity buffer (lookahead = 1 slot),
// with wave-uniform base addressing (saddr + lane voffset).
// cost [B=2, D=64, H=384, W=768] fp32, weights [B, 75, H, W] fp32.
// out[b,d,h,w] = sum_{i,j in 5x5} w0*c[d-1,h+i-2,w+j-2] + w1*c[d,..] + w2*c[d+1,..]

#define B_ 2
#define D_ 64
#define H_ 384
#define W_ 768
static constexpr int HW    = H_ * W_;
static constexpr int DPT   = 8;          // disparities per thread
static constexpr int NTY   = D_ / DPT;   // 8 waves
static constexpr int WT    = 64;
static constexpr int HSEG  = 8;          // output rows per block
static constexpr int RITER = HSEG + 4;   // 12 streamed input rows (even: parity unroll x2)
static constexpr int LROW  = 72;         // floats per LDS plane row
static constexpr int LPL   = 66;         // 0 = zero(d=-1), 1..64 = d, 65 = zero(d=64)
static constexpr int NCH_C = 18;         // 1 KiB chunks per cost-row stage

__device__ __forceinline__ void gld_lds16(const float* g, float* l) {
  __builtin_amdgcn_global_load_lds((const __attribute__((address_space(1))) unsigned int*)g,
                                   (__attribute__((address_space(3))) unsigned int*)l,
                                   16, 0, 0);
}

__global__ __launch_bounds__(512, 4) void lga_pass(const float* __restrict__ src,
                                                   const float* __restrict__ wts,
                                                   float* __restrict__ dst) {
  __shared__ float cl[2][LPL * LROW];     // 38016 B

  const int tx = threadIdx.x;             // 0..63 (lane; wave = ty)
  const int ty = threadIdx.y;             // 0..7
  const int bx = blockIdx.x;
  const int w0 = bx * WT, w = w0 + tx;
  const int hs = blockIdx.y * HSEG;
  const int b  = blockIdx.z;
  const int d0 = ty * DPT;

  const float* sb  = src + (size_t)b * D_ * HW;
  const float* wtb = wts + (size_t)b * 75 * HW;   // wave-uniform base; lane adds [w]

  // one-time zero of the d-pad planes (rows 0 and 65 of both buffers)
  {
    const int flat = ty * WT + tx;
    if (flat < 2 * 2 * LROW) {
      const int q   = flat / (2 * LROW);
      const int rem = flat - q * (2 * LROW);
      const int row = (rem >= LROW) ? (LPL - 1) : 0;
      const int col = (rem >= LROW) ? rem - LROW : rem;
      cl[q][row * LROW + col] = 0.f;
    }
  }

  // async stage of one cost row (64 planes x 288 B) into buffer `buf`
  auto stage_c = [&](int buf, int h_in) {
#pragma unroll
    for (int q = 0; q < 3; ++q) {
      const int c = ty + q * 8;                    // chunk id, wave-uniform
      if (c < NCH_C) {
        const int G = c * 64 + tx;
        const int d = G / NCH_C;
        const int k = G - d * NCH_C;
        long idx = (long)d * HW + (long)h_in * W_ + (w0 - 4) + (k << 2);
        idx = idx < 0 ? 0 : idx;
        const long mx = (long)D_ * HW - 4;
        idx = idx > mx ? mx : idx;
        gld_lds16(sb + idx, &cl[buf][LROW + c * 256]);
      }
    }
  };

  // load 15 weights for slot s (tap row 4-s), output row o: uniform base + [w]
  auto loadW = [&](float (&Wq)[15], int s, int o) {
    const int ib = (4 - s) * 5;
#pragma unroll
    for (int g = 0; g < 3; ++g)
#pragma unroll
      for (int j = 0; j < 5; ++j) {
        const float* p = wtb + (size_t)(ib + j + 25 * g) * HW + (size_t)o * W_;
        Wq[g * 5 + j] = p[w];
      }
  };

  // prologue: stage row 0 into buf 0
  {
    const int h0 = hs - 2;
    if (h0 >= 0) stage_c(0, h0);
  }
  __syncthreads();

  float acc[5][DPT];
#pragma unroll
  for (int s = 0; s < 5; ++s)
#pragma unroll
    for (int k = 0; k < DPT; ++k) acc[s][k] = 0.f;

  float Wa[15], Wb[15];
  int n = 0;

  // one input-row iteration; WX serves even slots (0,2,4), WY odd slots (1,3).
  // Parity of the physical buffers flips every iteration (5 slots, odd count),
  // handled by calling body(r,Wa,Wb) / body(r+1,Wb,Wa).
  auto body = [&](int r, float (&WX)[15], float (&WY)[15]) {
    // stage next cost row (fire-and-forget; drained by this iter's barrier)
    if (r + 1 < RITER) {
      const int h_nx = hs - 2 + r + 1;
      if ((unsigned)h_nx < (unsigned)H_) stage_c(n ^ 1, h_nx);
    }

    const int  h_in = hs - 2 + r;
    const bool hv   = (unsigned)h_in < (unsigned)H_;   // wave-uniform

    float vv[5][DPT + 2];
    if (hv) {
      float* cur = cl[n];
      // w-edge zero padding: each wave zeroes halo cols of the planes it reads
      if (bx == 0 && tx < 20)
        cur[(d0 + (tx >> 1)) * LROW + 2 + (tx & 1)] = 0.f;
      if (bx == (W_ / WT - 1) && tx < 20)
        cur[(d0 + (tx >> 1)) * LROW + 68 + (tx & 1)] = 0.f;
      // vv[j][m] = cost[d0-1+m, h_in, w+j-2] (ds_read with imm offsets)
      const float* vbase = cur + d0 * LROW + tx + 2;
#pragma unroll
      for (int j = 0; j < 5; ++j)
#pragma unroll
        for (int m = 0; m < DPT + 2; ++m)
          vv[j][m] = vbase[m * LROW + j];
    }

    auto fmaSlot = [&](float (&a)[DPT], const float (&Wq)[15]) {
#pragma unroll
      for (int j = 0; j < 5; ++j)
#pragma unroll
        for (int k = 0; k < DPT; ++k)
          a[k] = fmaf(Wq[j], vv[j][k],
                 fmaf(Wq[5 + j], vv[j][k + 1],
                 fmaf(Wq[10 + j], vv[j][k + 2], a[k])));
    };

    // interleaved: issue slot s+1's 15 loads, then run slot s's 120 FMAs.
    // slot s valid iff (r-4+s) in [0,HSEG); o(s) = hs+r-4+s.
    if ((unsigned)(r - 3) < (unsigned)HSEG) loadW(WY, 1, hs + r - 3);
    if (hv && (unsigned)(r - 4) < (unsigned)HSEG) fmaSlot(acc[0], WX);

    if ((unsigned)(r - 2) < (unsigned)HSEG) loadW(WX, 2, hs + r - 2);
    if (hv && (unsigned)(r - 3) < (unsigned)HSEG) fmaSlot(acc[1], WY);

    if ((unsigned)(r - 1) < (unsigned)HSEG) loadW(WY, 3, hs + r - 1);
    if (hv && (unsigned)(r - 2) < (unsigned)HSEG) fmaSlot(acc[2], WX);

    if ((unsigned)(r - 0) < (unsigned)HSEG) loadW(WX, 4, hs + r - 0);
    if (hv && (unsigned)(r - 1) < (unsigned)HSEG) fmaSlot(acc[3], WY);

    // next iter's slot 0 (o = hs+(r+1)-4); barrier drain absorbs its latency
    if ((unsigned)(r - 3) < (unsigned)HSEG) loadW(WY, 0, hs + r - 3);
    if (hv && (unsigned)(r - 0) < (unsigned)HSEG) fmaSlot(acc[4], WX);

    // slot 0 complete -> write output row hs+r-4 (uniform base + [w])
    if (r >= 4) {
      const int o = hs + r - 4;
#pragma unroll
      for (int k = 0; k < DPT; ++k) {
        float* dp = dst + (((size_t)b * D_ + d0 + k) * H_ + o) * W_;
        dp[w] = acc[0][k];
      }
    }

    // rotate accumulator slots (static indices)
#pragma unroll
    for (int s = 0; s < 4; ++s)
#pragma unroll
      for (int k = 0; k < DPT; ++k) acc[s][k] = acc[s + 1][k];
#pragma unroll
    for (int k = 0; k < DPT; ++k) acc[4][k] = 0.f;

    __syncthreads();   // drains staged loads; swap cost buffers
    n ^= 1;
  };

#pragma unroll 1
  for (int r = 0; r < RITER; r += 2) {
    body(r,     Wa, Wb);
    body(r + 1, Wb, Wa);
  }
}

extern "C" void kernel_launch(void* const* d_in, const int* in_sizes, int n_in,
                              void* d_out, int out_size, void* d_ws, size_t ws_size,
                              hipStream_t stream) {
  const float* cost = (const float*)d_in[0];
  const float* wts  = (const float*)d_in[1];
  float* out = (float*)d_out;
  float* ws  = (float*)d_ws;

  dim3 grid(W_ / WT, H_ / HSEG, B_);   // 12 x 48 x 2 = 1152 blocks
  dim3 block(WT, NTY);                 // 64 x 8 = 512 threads

  lga_pass<<<grid, block, 0, stream>>>(cost, wts, out);
  lga_pass<<<grid, block, 0, stream>>>(out, wts, ws);
  lga_pass<<<grid, block, 0, stream>>>(ws, wts, out);
}

// Round 9
// 640.299 us; speedup vs baseline: 2.5873x; 2.5873x over previous
//
#include <hip/hip_runtime.h>

// LGA3: 3 chained local-guided-aggregation passes, rolling-accumulator stencil.
// Cost planes in double-buffered LDS via global_load_lds (write-once per buffer,
// barrier-separated — NO other LDS writes anywhere). Zero-padding (d/h/w edges)
// enforced by register cndmask after the LDS read, not by writing LDS.
// Weights: all 75 loads batch-issued per iteration into statically-indexed regs
// (75-deep MLP per wave), wave-uniform row bases.
// cost [B=2, D=64, H=384, W=768] fp32, weights [B, 75, H, W] fp32.
// out[b,d,h,w] = sum_{i,j in 5x5} w0*c[d-1,h+i-2,w+j-2] + w1*c[d,..] + w2*c[d+1,..]

#define B_ 2
#define D_ 64
#define H_ 384
#define W_ 768
static constexpr int HW    = H_ * W_;
static constexpr int DPT   = 8;          // disparities per thread
static constexpr int NTY   = D_ / DPT;   // 8 waves
static constexpr int WT    = 64;
static constexpr int HSEG  = 8;          // output rows per block
static constexpr int RITER = HSEG + 4;   // 12 streamed input rows
static constexpr int LROW  = 72;         // floats per LDS plane row
static constexpr int LPL   = 66;         // row 0 (d=-1 pad) / rows 1..64 staged / row 65 (d=64 pad)
static constexpr int NCH_C = 18;         // 1 KiB chunks per cost-row stage

__device__ __forceinline__ void gld_lds16(const float* g, float* l) {
  __builtin_amdgcn_global_load_lds((const __attribute__((address_space(1))) unsigned int*)g,
                                   (__attribute__((address_space(3))) unsigned int*)l,
                                   16, 0, 0);
}

__global__ __launch_bounds__(512, 1) void lga_pass(const float* __restrict__ src,
                                                   const float* __restrict__ wts,
                                                   float* __restrict__ dst) {
  __shared__ float cl[2][LPL * LROW];     // 38016 B; rows 0/65 never written, never trusted

  const int tx = threadIdx.x;             // 0..63 (lane; wave = ty)
  const int ty = threadIdx.y;             // 0..7
  const int w0 = blockIdx.x * WT, w = w0 + tx;
  const int hs = blockIdx.y * HSEG;
  const int b  = blockIdx.z;
  const int d0 = ty * DPT;

  const float* sb  = src + (size_t)b * D_ * HW;
  const float* wtb = wts + (size_t)b * 75 * HW;    // uniform base; lane adds offset

  const bool has_lo = (d0 > 0);           // plane d0-1 exists
  const bool has_hi = (d0 + DPT < D_);    // plane d0+DPT exists
  bool wok[5];
#pragma unroll
  for (int j = 0; j < 5; ++j) wok[j] = (unsigned)(w + j - 2) < (unsigned)W_;

  // prologue: stage input row hs-2 into buf 0 (rows 1..64)
  {
    const int h0 = hs - 2;
    if (h0 >= 0) {
#pragma unroll
      for (int q = 0; q < 3; ++q) {
        const int c = ty + q * 8;                  // wave-uniform chunk id
        if (c < NCH_C) {
          const int G = c * 64 + tx;
          const int d = G / NCH_C;
          const int k = G - d * NCH_C;
          long idx = (long)d * HW + (long)h0 * W_ + (w0 - 4) + (k << 2);
          idx = idx < 0 ? 0 : idx;
          const long mx = (long)D_ * HW - 4;
          idx = idx > mx ? mx : idx;
          gld_lds16(sb + idx, &cl[0][LROW + c * 256]);
        }
      }
    }
  }
  __syncthreads();

  float acc[5][DPT];
#pragma unroll
  for (int s = 0; s < 5; ++s)
#pragma unroll
    for (int k = 0; k < DPT; ++k) acc[s][k] = 0.f;

  int n = 0;
#pragma unroll 1
  for (int r = 0; r < RITER; ++r) {
    // ---- 1. batch weight prefetch: all 75 loads, slot order (earliest use first)
    float W[75];
#pragma unroll
    for (int s = 0; s < 5; ++s) {
      if ((unsigned)(r - 4 + s) < (unsigned)HSEG) {       // wave-uniform
        const int o     = hs + r - 4 + s;
        const int ib    = (4 - s) * 5;
        const float* wr = wtb + (size_t)o * W_;           // uniform row base
#pragma unroll
        for (int g = 0; g < 3; ++g)
#pragma unroll
          for (int j = 0; j < 5; ++j)
            W[s * 15 + g * 5 + j] = wr[(size_t)(ib + j + 25 * g) * HW + w];
      }
    }

    // ---- 2. async stage of next input row into the other buffer
    if (r + 1 < RITER) {
      const int h_nx = hs - 2 + r + 1;
      if ((unsigned)h_nx < (unsigned)H_) {                // wave-uniform
#pragma unroll
        for (int q = 0; q < 3; ++q) {
          const int c = ty + q * 8;
          if (c < NCH_C) {
            const int G = c * 64 + tx;
            const int d = G / NCH_C;
            const int k = G - d * NCH_C;
            long idx = (long)d * HW + (long)h_nx * W_ + (w0 - 4) + (k << 2);
            idx = idx < 0 ? 0 : idx;                      // both clamps (R7 lesson)
            const long mx = (long)D_ * HW - 4;
            idx = idx > mx ? mx : idx;
            gld_lds16(sb + idx, &cl[n ^ 1][LROW + c * 256]);
          }
        }
      }
    }

    // ---- 3. LDS -> vv (raw read, then register masking for d/w padding)
    const int  h_in = hs - 2 + r;
    const bool hv   = (unsigned)h_in < (unsigned)H_;      // wave-uniform
    float vv[5][DPT + 2];
    if (hv) {
      const float* vbase = cl[n] + d0 * LROW + tx + 2;
#pragma unroll
      for (int j = 0; j < 5; ++j)
#pragma unroll
        for (int m = 0; m < DPT + 2; ++m) {
          const float v = vbase[m * LROW + j];
          bool ok = wok[j];
          if (m == 0)       ok = ok && has_lo;
          if (m == DPT + 1) ok = ok && has_hi;
          vv[j][m] = ok ? v : 0.f;
        }
    }

    // ---- 4. per-slot FMAs (slot s -> output row hs+r-4+s, tap row 4-s)
#pragma unroll
    for (int s = 0; s < 5; ++s) {
      if (hv && (unsigned)(r - 4 + s) < (unsigned)HSEG) {
#pragma unroll
        for (int j = 0; j < 5; ++j)
#pragma unroll
          for (int k = 0; k < DPT; ++k)
            acc[s][k] = fmaf(W[s * 15 + j],      vv[j][k],
                        fmaf(W[s * 15 + 5 + j],  vv[j][k + 1],
                        fmaf(W[s * 15 + 10 + j], vv[j][k + 2], acc[s][k])));
      }
    }

    // ---- 5. slot 0 complete -> write output row hs+r-4 (uniform-base stores)
    if (r >= 4) {
      const int o = hs + r - 4;
#pragma unroll
      for (int k = 0; k < DPT; ++k) {
        float* dp = dst + (((size_t)b * D_ + d0 + k) * H_ + o) * W_;
        dp[w] = acc[0][k];
      }
    }

    // ---- 6. rotate accumulator slots (static indices)
#pragma unroll
    for (int s = 0; s < 4; ++s)
#pragma unroll
      for (int k = 0; k < DPT; ++k) acc[s][k] = acc[s + 1][k];
#pragma unroll
    for (int k = 0; k < DPT; ++k) acc[4][k] = 0.f;

    __syncthreads();   // drains staged loads (vmcnt) for ALL waves; swap buffers
    n ^= 1;
  }
}

extern "C" void kernel_launch(void* const* d_in, const int* in_sizes, int n_in,
                              void* d_out, int out_size, void* d_ws, size_t ws_size,
                              hipStream_t stream) {
  const float* cost = (const float*)d_in[0];
  const float* wts  = (const float*)d_in[1];
  float* out = (float*)d_out;
  float* ws  = (float*)d_ws;

  dim3 grid(W_ / WT, H_ / HSEG, B_);   // 12 x 48 x 2 = 1152 blocks
  dim3 block(WT, NTY);                 // 64 x 8 = 512 threads

  lga_pass<<<grid, block, 0, stream>>>(cost, wts, out);
  lga_pass<<<grid, block, 0, stream>>>(out, wts, ws);
  lga_pass<<<grid, block, 0, stream>>>(ws, wts, out);
}